// Round 3
// baseline (802.545 us; speedup 1.0000x reference)
//
#include <hip/hip_runtime.h>
#include <stdint.h>
#include <stddef.h>

#define DEV static __device__ __forceinline__

typedef __attribute__((ext_vector_type(8))) short bf16x8;
typedef __attribute__((ext_vector_type(4))) float f32x4;

// ---------- small helpers ----------
DEV float bf2f(unsigned short u){ union{unsigned int i; float f;} v; v.i = ((unsigned int)u)<<16; return v.f; }
DEV unsigned short f2bf(float f){ union{float f; unsigned int i;} v; v.f=f; unsigned int i=v.i;
  return (unsigned short)((i + 0x7FFFu + ((i>>16)&1u)) >> 16); }
// monotone float<->uint encoding for atomic min/max
DEV unsigned int fenc(float x){ unsigned int i = __float_as_uint(x); return (i & 0x80000000u) ? ~i : (i | 0x80000000u); }
DEV float fdec(unsigned int e){ unsigned int i = (e & 0x80000000u) ? (e & 0x7FFFFFFFu) : ~e; return __uint_as_float(i); }

DEV float waveSum(float s){
  for (int m=32;m;m>>=1) s += __shfl_xor(s, m, 64);
  return s;
}

DEV float blockSum(float v, float* red){
  int t = threadIdx.x;
  red[t] = v; __syncthreads();
  for (int k=128;k>0;k>>=1){ if (t<k) red[t] += red[t+k]; __syncthreads(); }
  float r = red[0]; __syncthreads();
  return r;
}

// XLA ErfInv32 (Giles polynomial, log1p variant)
DEV float erfinv_f(float x){
  float w = -log1pf(-__fmul_rn(x,x));
  float p;
  if (w < 5.0f){
    w = w - 2.5f;
    p = 2.81022636e-08f;
    p = 3.43273939e-07f + p*w;
    p = -3.5233877e-06f + p*w;
    p = -4.39150654e-06f + p*w;
    p = 0.00021858087f + p*w;
    p = -0.00125372503f + p*w;
    p = -0.00417768164f + p*w;
    p = 0.246640727f + p*w;
    p = 1.50140941f + p*w;
  } else {
    w = sqrtf(w) - 3.0f;
    p = -0.000200214257f;
    p = 0.000100950558f + p*w;
    p = 0.00134934322f + p*w;
    p = -0.00367342844f + p*w;
    p = 0.00573950773f + p*w;
    p = -0.0076224613f + p*w;
    p = 0.00943887047f + p*w;
    p = 1.00167406f + p*w;
    p = 2.83297682f + p*w;
  }
  return p*x;
}

// ---------- constants ----------
#define BN_TOT 32768      // B*n_patches
#define DIM 768
#define NCLS 201
#define KP 5
#define CKPAD 1024        // padded proto-row count (>=1005)

// ---------- kernels ----------

// canonicalize labels (int64 vs int32 layout; detection is deterministic)
__global__ void k_labels(const int* __restrict__ raw, int* __restrict__ lab){
  if (threadIdx.x == 0){
    bool is64 = true;
    for (int i=0;i<8;i++){
      int lo = raw[2*i], hi = raw[2*i+1];
      if (hi != 0 || lo < 0 || lo >= NCLS-1){ is64 = false; break; }
    }
    for (int i=0;i<32;i++) lab[i] = is64 ? raw[2*i] : raw[i];
  }
}

// init accumulators (re-run every call: idempotent)
__global__ void k_init(unsigned int* ipl_enc, int* cnt, int* cur, int* present,
                       unsigned int* minmax, float* meansum){
  int i = blockIdx.x*256 + threadIdx.x;
  if (i < 32*CKPAD) ipl_enc[i] = 0u;             // < any encoded real value
  if (i < NCLS){ cnt[i]=0; cur[i]=0; present[i]=0; }
  if (i < DIM) meansum[i] = 0.f;
  if (i == 0){ minmax[0]=0xFFFFFFFFu; minmax[1]=0u; }
}

// normalize prototypes -> bf16, zero-pad rows [1005,1024)
__global__ void k_proto(const float* __restrict__ protos, unsigned short* __restrict__ protn){
  int row = blockIdx.x;           // 0..1023
  int l = threadIdx.x;            // 64
  if (row >= NCLS*KP){
    for (int j=0;j<12;j++) protn[(size_t)row*DIM + l + j*64] = 0;
    return;
  }
  const float* p = protos + (size_t)row*DIM;
  float x[12]; float s = 0.f;
  for (int j=0;j<12;j++){ x[j] = p[l + j*64]; s += x[j]*x[j]; }
  s = waveSum(s);
  float inv = 1.0f / fmaxf(sqrtf(s), 1e-12f);
  for (int j=0;j<12;j++) protn[(size_t)row*DIM + l + j*64] = f2bf(x[j]*inv);
}

// column sums of X (for mean)
__global__ void k_mean(const float* __restrict__ X, float* __restrict__ meansum){
  int t = threadIdx.x;
  const float* base = X + (size_t)blockIdx.x*128*DIM;
  float a0=0.f, a1=0.f, a2=0.f;
  for (int r=0;r<128;r++){
    const float* row = base + (size_t)r*DIM;
    a0 += row[t]; a1 += row[t+256]; a2 += row[t+512];
  }
  atomicAdd(&meansum[t], a0);
  atomicAdd(&meansum[t+256], a1);
  atomicAdd(&meansum[t+512], a2);
}

// transpose X -> hiT/loT bf16 split, [DIM][BN_TOT]
__global__ void k_trans(const float* __restrict__ X, unsigned short* __restrict__ hiT,
                        unsigned short* __restrict__ loT){
  __shared__ float tile[64][65];
  int n0 = blockIdx.x*64, c0 = blockIdx.y*64;
  int t = threadIdx.x;
  for (int i=0;i<16;i++){
    int idx = t + i*256; int r = idx>>6, c = idx&63;
    tile[r][c] = X[(size_t)(n0+r)*DIM + c0+c];
  }
  __syncthreads();
  for (int i=0;i<16;i++){
    int idx = t + i*256; int c = idx>>6, n = idx&63;
    float x = tile[n][c];
    unsigned short h = f2bf(x);
    float hf = bf2f(h);
    unsigned short lo = f2bf(x - hf);
    size_t o = (size_t)(c0+c)*BN_TOT + n0+n;
    hiT[o] = h; loT[o] = lo;
  }
}

// row-normalize patch tokens -> bf16
__global__ void k_ptn(const float* __restrict__ X, unsigned short* __restrict__ ptn){
  int row = blockIdx.x*4 + (threadIdx.x>>6);
  int l = threadIdx.x & 63;
  const float* p = X + (size_t)row*DIM;
  float x[12]; float s = 0.f;
  for (int j=0;j<12;j++){ x[j] = p[l + j*64]; s += x[j]*x[j]; }
  s = waveSum(s);
  float inv = 1.0f / fmaxf(sqrtf(s), 1e-12f);
  for (int j=0;j<12;j++) ptn[(size_t)row*DIM + l + j*64] = f2bf(x[j]*inv);
}

// main logits GEMM with fused per-image column max
__global__ __launch_bounds__(256) void k_gemm_logits(const unsigned short* __restrict__ A,
                                                     const unsigned short* __restrict__ Bt,
                                                     unsigned int* __restrict__ ipl_enc){
  __shared__ __align__(16) unsigned short As[128][32];
  __shared__ __align__(16) unsigned short Bs[128][32];
  __shared__ float red[2][2][64];
  int nb = blockIdx.x, mb = blockIdx.y;
  int t = threadIdx.x;
  int w = t>>6, l = t&63;
  int wr = w>>1, wc = w&1;
  f32x4 acc[4][4];
  #pragma unroll
  for (int m=0;m<4;m++)
    #pragma unroll
    for (int n=0;n<4;n++){ acc[m][n][0]=0.f; acc[m][n][1]=0.f; acc[m][n][2]=0.f; acc[m][n][3]=0.f; }

  for (int kt=0; kt<24; kt++){
    int k0 = kt*32;
    __syncthreads();
    #pragma unroll
    for (int i=0;i<2;i++){
      int ch = t + i*256;
      int r = ch>>2, co = (ch&3)*8;
      *(uint4*)&As[r][co] = *(const uint4*)&A[(size_t)(mb*128 + r)*DIM + k0 + co];
      *(uint4*)&Bs[r][co] = *(const uint4*)&Bt[(size_t)(nb*128 + r)*DIM + k0 + co];
    }
    __syncthreads();
    bf16x8 a[4], b[4];
    #pragma unroll
    for (int m=0;m<4;m++) a[m] = *(const bf16x8*)&As[wr*64 + m*16 + (l&15)][(l>>4)*8];
    #pragma unroll
    for (int n=0;n<4;n++) b[n] = *(const bf16x8*)&Bs[wc*64 + n*16 + (l&15)][(l>>4)*8];
    #pragma unroll
    for (int m=0;m<4;m++)
      #pragma unroll
      for (int n=0;n<4;n++)
        acc[m][n] = __builtin_amdgcn_mfma_f32_16x16x32_bf16(a[m], b[n], acc[m][n], 0,0,0);
  }
  // per-column max over this block's 128 rows
  float vmax[4];
  #pragma unroll
  for (int n=0;n<4;n++){
    float v = -1e30f;
    #pragma unroll
    for (int m=0;m<4;m++)
      #pragma unroll
      for (int r=0;r<4;r++) v = fmaxf(v, acc[m][n][r]);
    v = fmaxf(v, __shfl_xor(v, 16, 64));
    v = fmaxf(v, __shfl_xor(v, 32, 64));
    vmax[n] = v;
  }
  __syncthreads();
  if (l < 16){
    #pragma unroll
    for (int n=0;n<4;n++) red[wc][wr][n*16 + l] = vmax[n];
  }
  __syncthreads();
  if (t < 128){
    int wcc = t>>6, col = t&63;
    float v = fmaxf(red[wcc][0][col], red[wcc][1][col]);
    int gcol = nb*128 + wcc*64 + col;
    if (gcol < NCLS*KP){
      int b = (mb*128) >> 10;
      atomicMax(&ipl_enc[b*CKPAD + gcol], fenc(v));
    }
  }
}

// G split-bf16 GEMM: Gpart[s] tile = hi^T hi + hi^T lo + lo^T hi  (K chunk 4096)
__global__ __launch_bounds__(256) void k_gemm_G(const unsigned short* __restrict__ hiT,
                                                const unsigned short* __restrict__ loT,
                                                float* __restrict__ Gpart){
  __shared__ __align__(16) unsigned short Ahi[128][32];
  __shared__ __align__(16) unsigned short Alo[128][32];
  __shared__ __align__(16) unsigned short Bhi[128][32];
  __shared__ __align__(16) unsigned short Blo[128][32];
  int tid = blockIdx.x; int ib = tid/6, jb = tid%6;
  int s = blockIdx.y;
  int t = threadIdx.x, w = t>>6, l = t&63, wr = w>>1, wc = w&1;
  f32x4 acc[4][4];
  #pragma unroll
  for (int m=0;m<4;m++)
    #pragma unroll
    for (int n=0;n<4;n++){ acc[m][n][0]=0.f; acc[m][n][1]=0.f; acc[m][n][2]=0.f; acc[m][n][3]=0.f; }

  for (int kt=0; kt<128; kt++){
    size_t k0 = (size_t)s*4096 + (size_t)kt*32;
    __syncthreads();
    #pragma unroll
    for (int i=0;i<2;i++){
      int ch = t + i*256; int r = ch>>2, co = (ch&3)*8;
      size_t ga = (size_t)(ib*128 + r)*BN_TOT + k0 + co;
      size_t gb = (size_t)(jb*128 + r)*BN_TOT + k0 + co;
      *(uint4*)&Ahi[r][co] = *(const uint4*)&hiT[ga];
      *(uint4*)&Alo[r][co] = *(const uint4*)&loT[ga];
      *(uint4*)&Bhi[r][co] = *(const uint4*)&hiT[gb];
      *(uint4*)&Blo[r][co] = *(const uint4*)&loT[gb];
    }
    __syncthreads();
    bf16x8 ah[4], al[4], bh[4], bl[4];
    #pragma unroll
    for (int m=0;m<4;m++){
      ah[m] = *(const bf16x8*)&Ahi[wr*64 + m*16 + (l&15)][(l>>4)*8];
      al[m] = *(const bf16x8*)&Alo[wr*64 + m*16 + (l&15)][(l>>4)*8];
    }
    #pragma unroll
    for (int n=0;n<4;n++){
      bh[n] = *(const bf16x8*)&Bhi[wc*64 + n*16 + (l&15)][(l>>4)*8];
      bl[n] = *(const bf16x8*)&Blo[wc*64 + n*16 + (l&15)][(l>>4)*8];
    }
    #pragma unroll
    for (int m=0;m<4;m++)
      #pragma unroll
      for (int n=0;n<4;n++){
        acc[m][n] = __builtin_amdgcn_mfma_f32_16x16x32_bf16(ah[m], bh[n], acc[m][n], 0,0,0);
        acc[m][n] = __builtin_amdgcn_mfma_f32_16x16x32_bf16(ah[m], bl[n], acc[m][n], 0,0,0);
        acc[m][n] = __builtin_amdgcn_mfma_f32_16x16x32_bf16(al[m], bh[n], acc[m][n], 0,0,0);
      }
  }
  float* out = Gpart + (size_t)s*DIM*DIM;
  #pragma unroll
  for (int m=0;m<4;m++)
    #pragma unroll
    for (int n=0;n<4;n++)
      #pragma unroll
      for (int r=0;r<4;r++){
        int row = ib*128 + wr*64 + m*16 + (l>>4)*4 + r;
        int col = jb*128 + wc*64 + n*16 + (l&15);
        out[(size_t)row*DIM + col] = acc[m][n][r];
      }
}

// G' = sum(Gpart)/N - mu mu^T
__global__ void k_gfix(const float* __restrict__ Gpart, const float* __restrict__ meansum,
                       float* __restrict__ G){
  int i = blockIdx.x*256 + threadIdx.x;   // < 768*768 exactly
  int r = i/DIM, c = i%DIM;
  float s = 0.f;
  #pragma unroll
  for (int p=0;p<8;p++) s += Gpart[(size_t)p*DIM*DIM + i];
  const float invN = 1.0f/32768.0f;
  float mr = meansum[r]*invN, mc = meansum[c]*invN;
  G[i] = s*invN - mr*mc;
}

// v0 = jax.random.normal(key(1), (768,)) — PARTITIONABLE threefry path
// (modern JAX default: per element i, counter64 = i -> msg (hi,lo) = (0,i),
//  bits = out0 ^ out1 of threefry2x32(key=(0,1), msg))
__global__ void k_v0(float* __restrict__ v){
  int i = blockIdx.x*256 + threadIdx.x;
  if (i >= DIM) return;
  unsigned int ks[3] = {0u, 1u, 0x1BD11BDBu};   // 0 ^ 1 ^ 0x1BD11BDA
  const int rot0[4] = {13,15,26,6};
  const int rot1[4] = {17,29,16,24};
  unsigned int x0 = 0u, x1 = (unsigned int)i;
  x0 += ks[0]; x1 += ks[1];
  #pragma unroll
  for (int g=0; g<5; g++){
    const int* rr = (g&1) ? rot1 : rot0;
    #pragma unroll
    for (int j=0;j<4;j++){
      x0 += x1;
      x1 = (x1 << rr[j]) | (x1 >> (32-rr[j]));
      x1 ^= x0;
    }
    x0 += ks[(g+1)%3];
    x1 += ks[(g+2)%3] + (unsigned int)(g+1);
  }
  unsigned int b = x0 ^ x1;
  const float lo = __uint_as_float(0xBF7FFFFFu);      // nextafter(-1,0)
  const float sq2 = __uint_as_float(0x3FB504F3u);     // sqrt(2) f32
  float f = __uint_as_float((b>>9) | 0x3F800000u) - 1.0f;
  float u = __fadd_rn(__fmul_rn(f, 2.0f), lo);
  u = fmaxf(lo, u);
  v[i] = sq2 * erfinv_f(u);
}

// v_out = G * v_in   (one wave per row)
__global__ void k_mv(const float* __restrict__ G, const float* __restrict__ vin,
                     float* __restrict__ vout){
  __shared__ float vs[DIM];
  int t = threadIdx.x;
  for (int i=t;i<DIM;i+=256) vs[i] = vin[i];
  __syncthreads();
  int row = blockIdx.x*4 + (t>>6), l = t&63;
  const float* g = G + (size_t)row*DIM;
  float s = 0.f;
  for (int j=0;j<12;j++) s += g[l + j*64]*vs[l + j*64];
  s = waveSum(s);
  if (l==0) vout[row] = s;
}

// scal[0] = mu . v
__global__ void k_muv(const float* __restrict__ meansum, const float* __restrict__ v,
                      float* __restrict__ scal){
  __shared__ float red[256];
  int t = threadIdx.x;
  float s = 0.f;
  for (int i=t;i<DIM;i+=256) s += meansum[i]*(1.0f/32768.0f)*v[i];
  float r = blockSum(s, red);
  if (t==0) scal[0] = r;
}

// u[n] = X[n,:].v - mu.v
__global__ void k_u(const unsigned short* __restrict__ hiT, const unsigned short* __restrict__ loT,
                    const float* __restrict__ v, const float* __restrict__ scal,
                    float* __restrict__ u){
  __shared__ float vs[DIM];
  int t = threadIdx.x;
  for (int i=t;i<DIM;i+=256) vs[i] = v[i];
  __syncthreads();
  size_t n = (size_t)blockIdx.x*256 + t;
  float acc = 0.f;
  for (int c=0;c<DIM;c++){
    size_t o = (size_t)c*BN_TOT + n;
    acc += (bf2f(hiT[o]) + bf2f(loT[o])) * vs[c];
  }
  u[n] = acc - scal[0];
}

__global__ void k_minmax(const float* __restrict__ u, unsigned int* __restrict__ minmax){
  int i = blockIdx.x*256 + threadIdx.x;
  float x = u[i];
  float mn = x, mx = x;
  for (int m=32;m;m>>=1){
    mn = fminf(mn, __shfl_xor(mn, m, 64));
    mx = fmaxf(mx, __shfl_xor(mx, m, 64));
  }
  __shared__ float smn[4], smx[4];
  int w = threadIdx.x>>6;
  if ((threadIdx.x&63)==0){ smn[w]=mn; smx[w]=mx; }
  __syncthreads();
  if (threadIdx.x==0){
    for (int k=1;k<4;k++){ mn = fminf(mn, smn[k]); mx = fmaxf(mx, smx[k]); }
    atomicMin(&minmax[0], fenc(mn));
    atomicMax(&minmax[1], fenc(mx));
  }
}

// patch labels + per-class counts (fg only)
__global__ void k_pl(const float* __restrict__ u, const int* __restrict__ labels,
                     const unsigned int* __restrict__ minmax, int* __restrict__ pl,
                     int* __restrict__ cnt){
  int n = blockIdx.x*256 + threadIdx.x;
  float umin = fdec(minmax[0]), umax = fdec(minmax[1]);
  float us = (u[n]-umin)/(umax-umin);
  int c = (us < 0.5f) ? labels[n>>10] : (NCLS-1);
  pl[n] = c;
  if (c < NCLS-1) atomicAdd(&cnt[c], 1);
}

// prefix offsets + present bitmap
__global__ void k_offs(const int* __restrict__ cnt, int* __restrict__ offs,
                       const int* __restrict__ labels, int* __restrict__ present){
  if (threadIdx.x == 0){
    int acc = 0;
    for (int c=0;c<NCLS-1;c++){ offs[c] = acc; acc += cnt[c]; }
    offs[NCLS-1] = acc;
  }
  if (threadIdx.x < 32) atomicOr(&present[labels[threadIdx.x]], 1);
}

__global__ void k_scatter(const int* __restrict__ pl, const int* __restrict__ offs,
                          int* __restrict__ cur, int* __restrict__ idx){
  int n = blockIdx.x*256 + threadIdx.x;
  int c = pl[n];
  if (c < NCLS-1){
    int p = offs[c] + atomicAdd(&cur[c], 1);
    idx[p] = n;
  }
}

// own-class logits -> q0 = exp(L/eps), stored in class-sorted order
__global__ void k_qlog(const int* __restrict__ idx, const int* __restrict__ offs,
                       const int* __restrict__ pl, const unsigned short* __restrict__ ptn,
                       const unsigned short* __restrict__ protn, float* __restrict__ q){
  int i = blockIdx.x*4 + (threadIdx.x>>6);
  int l = threadIdx.x & 63;
  int total = offs[NCLS-1];
  if (i >= total) return;
  int n = idx[i];
  int c = pl[n];
  const unsigned short* pr = ptn + (size_t)n*DIM;
  float x[12];
  for (int j=0;j<12;j++) x[j] = bf2f(pr[l + j*64]);
  for (int k=0;k<KP;k++){
    const unsigned short* wv = protn + (size_t)(c*KP + k)*DIM;
    float s = 0.f;
    for (int j=0;j<12;j++) s += x[j]*bf2f(wv[l + j*64]);
    s = waveSum(s);
    if (l==0) q[(size_t)i*KP + k] = expf(s*20.0f);
  }
}

// per-class sinkhorn in place on its sorted segment
__global__ void k_sink(const int* __restrict__ cnt, const int* __restrict__ offs,
                       float* __restrict__ q){
  __shared__ float red[256];
  __shared__ float colf[KP];
  int c = blockIdx.x;
  int nc = cnt[c];
  if (nc == 0) return;
  int n0 = offs[c];
  float* Q = q + (size_t)n0*KP;
  int t = threadIdx.x;
  int tot5 = nc*KP;
  float s = 0.f;
  for (int i=t;i<tot5;i+=256) s += Q[i];
  float total = blockSum(s, red);
  float sc = 1.0f/fmaxf(total, 1e-9f);
  for (int i=t;i<tot5;i+=256) Q[i] *= sc;
  __syncthreads();
  float ncf = (float)nc;
  for (int it=0; it<3; it++){
    float cs[KP] = {0,0,0,0,0};
    for (int i=t;i<nc;i+=256){
      const float* row = Q + (size_t)i*KP;
      #pragma unroll
      for (int k=0;k<KP;k++) cs[k] += row[k];
    }
    for (int k=0;k<KP;k++){
      float v = blockSum(cs[k], red);
      if (t==0) colf[k] = 1.0f/(fmaxf(v,1e-9f)*(float)KP);
    }
    __syncthreads();
    for (int i=t;i<nc;i+=256){
      float* row = Q + (size_t)i*KP;
      float qq[KP]; float rs = 0.f;
      #pragma unroll
      for (int k=0;k<KP;k++){ qq[k] = row[k]*colf[k]; rs += qq[k]; }
      float rf = 1.0f/(fmaxf(rs,1e-9f)*ncf);
      #pragma unroll
      for (int k=0;k<KP;k++) row[k] = qq[k]*rf;
    }
    __syncthreads();
  }
  for (int i=t;i<tot5;i+=256) Q[i] *= ncf;
}

// P_new[c,k,d] = sum over class-c rows of Q[n,k]*ptn[n,d]
__global__ void k_pnew(const int* __restrict__ cnt, const int* __restrict__ offs,
                       const int* __restrict__ present, const int* __restrict__ idx,
                       const float* __restrict__ q, const unsigned short* __restrict__ ptn,
                       float* __restrict__ P){
  int c = blockIdx.y, dc = blockIdx.x;
  if (!present[c]) return;
  int nc = cnt[c], n0 = offs[c];
  int t = threadIdx.x;
  int d = dc*128 + (t & 127);
  int half = t >> 7;
  float acc[KP] = {0,0,0,0,0};
  for (int i=half; i<nc; i+=2){
    int n = idx[n0+i];
    const float* qq = q + (size_t)(n0+i)*KP;
    float x = bf2f(ptn[(size_t)n*DIM + d]);
    #pragma unroll
    for (int k=0;k<KP;k++) acc[k] += qq[k]*x;
  }
  __shared__ float red[KP][256];
  #pragma unroll
  for (int k=0;k<KP;k++) red[k][t] = acc[k];
  __syncthreads();
  if (half == 0){
    #pragma unroll
    for (int k=0;k<KP;k++)
      P[((size_t)c*KP + k)*DIM + d] = red[k][t] + red[k][t+128];
  }
}

// new_prototypes = present ? 0.9*p + 0.1*P_new : p
__global__ void k_ema(const float* __restrict__ protos, const float* __restrict__ P,
                      const int* __restrict__ present, float* __restrict__ out){
  int i = blockIdx.x*256 + threadIdx.x;
  if (i >= NCLS*KP*DIM) return;
  int c = i / (KP*DIM);
  float p = protos[i];
  out[i] = present[c] ? (0.9f*p + 0.1f*P[i]) : p;
}

// decode ipl + class_logits
__global__ void k_final(const unsigned int* __restrict__ ipl_enc, float* __restrict__ out){
  int i = blockIdx.x*256 + threadIdx.x;
  if (i < 32*NCLS*KP){
    int b = i / (NCLS*KP), ck = i % (NCLS*KP);
    out[32*NCLS + i] = fdec(ipl_enc[b*CKPAD + ck]);
  }
  if (i < 32*NCLS){
    int b = i / NCLS, c = i % NCLS;
    float s = 0.f;
    #pragma unroll
    for (int k=0;k<KP;k++) s += fdec(ipl_enc[b*CKPAD + c*KP + k]);
    out[b*NCLS + c] = s;
  }
}

// ---------- launch ----------
extern "C" void kernel_launch(void* const* d_in, const int* in_sizes, int n_in,
                              void* d_out, int out_size, void* d_ws, size_t ws_size,
                              hipStream_t stream){
  (void)in_sizes; (void)n_in; (void)out_size; (void)ws_size;
  const float* X = (const float*)d_in[0];
  const float* protos = (const float*)d_in[1];
  const int* labels_raw = (const int*)d_in[2];
  float* out = (float*)d_out;

  char* w = (char*)d_ws;
  size_t off = 0;
  auto alloc = [&](size_t bytes)->void*{
    void* p = (void*)(w + off);
    off = (off + bytes + 255) & ~(size_t)255;
    return p;
  };
  unsigned short* hiT   = (unsigned short*)alloc((size_t)DIM*BN_TOT*2);
  unsigned short* loT   = (unsigned short*)alloc((size_t)DIM*BN_TOT*2);
  unsigned short* ptn   = (unsigned short*)alloc((size_t)BN_TOT*DIM*2);
  unsigned short* protn = (unsigned short*)alloc((size_t)CKPAD*DIM*2);
  float* Gpart   = (float*)alloc((size_t)8*DIM*DIM*4);
  float* G       = (float*)alloc((size_t)DIM*DIM*4);
  float* meansum = (float*)alloc(DIM*4);
  float* vA      = (float*)alloc(DIM*4);
  float* vB      = (float*)alloc(DIM*4);
  float* scal    = (float*)alloc(256);
  float* u       = (float*)alloc(BN_TOT*4);
  int* pl        = (int*)alloc(BN_TOT*4);
  int* idx       = (int*)alloc(BN_TOT*4);
  float* q       = (float*)alloc((size_t)BN_TOT*KP*4);
  int* cnt       = (int*)alloc(1024);
  int* cur       = (int*)alloc(1024);
  int* offs      = (int*)alloc(1024);
  int* present   = (int*)alloc(1024);
  int* labc      = (int*)alloc(256);
  unsigned int* minmax  = (unsigned int*)alloc(256);
  unsigned int* ipl_enc = (unsigned int*)alloc((size_t)32*CKPAD*4);
  float* Pnew    = (float*)alloc((size_t)NCLS*KP*DIM*4);

  dim3 b256(256);
  k_labels<<<dim3(1), dim3(64), 0, stream>>>(labels_raw, labc);
  k_init<<<dim3(128), b256, 0, stream>>>(ipl_enc, cnt, cur, present, minmax, meansum);
  k_proto<<<dim3(CKPAD), dim3(64), 0, stream>>>(protos, protn);
  k_mean<<<dim3(256), b256, 0, stream>>>(X, meansum);
  k_trans<<<dim3(512,12), b256, 0, stream>>>(X, hiT, loT);
  k_ptn<<<dim3(8192), b256, 0, stream>>>(X, ptn);
  k_gemm_logits<<<dim3(8,256), b256, 0, stream>>>(ptn, protn, ipl_enc);
  k_gemm_G<<<dim3(36,8), b256, 0, stream>>>(hiT, loT, Gpart);
  k_gfix<<<dim3(2304), b256, 0, stream>>>(Gpart, meansum, G);
  k_v0<<<dim3(3), b256, 0, stream>>>(vA);
  for (int it=0; it<10; it++){
    float* src = (it&1) ? vB : vA;
    float* dst = (it&1) ? vA : vB;
    k_mv<<<dim3(192), b256, 0, stream>>>(G, src, dst);
  }
  k_muv<<<dim3(1), b256, 0, stream>>>(meansum, vA, scal);
  k_u<<<dim3(128), b256, 0, stream>>>(hiT, loT, vA, scal, u);
  k_minmax<<<dim3(128), b256, 0, stream>>>(u, minmax);
  k_pl<<<dim3(128), b256, 0, stream>>>(u, labc, minmax, pl, cnt);
  k_offs<<<dim3(1), b256, 0, stream>>>(cnt, offs, labc, present);
  k_scatter<<<dim3(128), b256, 0, stream>>>(pl, offs, cur, idx);
  k_qlog<<<dim3(8192), b256, 0, stream>>>(idx, offs, pl, ptn, protn, q);
  k_sink<<<dim3(200), b256, 0, stream>>>(cnt, offs, q);
  k_pnew<<<dim3(6,NCLS), b256, 0, stream>>>(cnt, offs, present, idx, q, ptn, Pnew);
  k_ema<<<dim3(3015), b256, 0, stream>>>(protos, Pnew, present, out + 32*NCLS + 32*NCLS*KP);
  k_final<<<dim3(126), b256, 0, stream>>>(ipl_enc, out);
}

// Round 4
// 576.903 us; speedup vs baseline: 1.3911x; 1.3911x over previous
//
#include <hip/hip_runtime.h>
#include <stdint.h>
#include <stddef.h>

#define DEV static __device__ __forceinline__

typedef __attribute__((ext_vector_type(8))) short bf16x8;
typedef __attribute__((ext_vector_type(4))) float f32x4;

// ---------- small helpers ----------
DEV float bf2f(unsigned short u){ union{unsigned int i; float f;} v; v.i = ((unsigned int)u)<<16; return v.f; }
DEV unsigned short f2bf(float f){ union{float f; unsigned int i;} v; v.f=f; unsigned int i=v.i;
  return (unsigned short)((i + 0x7FFFu + ((i>>16)&1u)) >> 16); }
// monotone float<->uint encoding for atomic min/max
DEV unsigned int fenc(float x){ unsigned int i = __float_as_uint(x); return (i & 0x80000000u) ? ~i : (i | 0x80000000u); }
DEV float fdec(unsigned int e){ unsigned int i = (e & 0x80000000u) ? (e & 0x7FFFFFFFu) : ~e; return __uint_as_float(i); }

DEV float waveSum(float s){
  for (int m=32;m;m>>=1) s += __shfl_xor(s, m, 64);
  return s;
}

DEV float blockSum(float v, float* red){
  int t = threadIdx.x;
  red[t] = v; __syncthreads();
  for (int k=128;k>0;k>>=1){ if (t<k) red[t] += red[t+k]; __syncthreads(); }
  float r = red[0]; __syncthreads();
  return r;
}

// XLA ErfInv32 (Giles polynomial, log1p variant)
DEV float erfinv_f(float x){
  float w = -log1pf(-__fmul_rn(x,x));
  float p;
  if (w < 5.0f){
    w = w - 2.5f;
    p = 2.81022636e-08f;
    p = 3.43273939e-07f + p*w;
    p = -3.5233877e-06f + p*w;
    p = -4.39150654e-06f + p*w;
    p = 0.00021858087f + p*w;
    p = -0.00125372503f + p*w;
    p = -0.00417768164f + p*w;
    p = 0.246640727f + p*w;
    p = 1.50140941f + p*w;
  } else {
    w = sqrtf(w) - 3.0f;
    p = -0.000200214257f;
    p = 0.000100950558f + p*w;
    p = 0.00134934322f + p*w;
    p = -0.00367342844f + p*w;
    p = 0.00573950773f + p*w;
    p = -0.0076224613f + p*w;
    p = 0.00943887047f + p*w;
    p = 1.00167406f + p*w;
    p = 2.83297682f + p*w;
  }
  return p*x;
}

// ---------- constants ----------
#define BN_TOT 32768      // B*n_patches
#define DIM 768
#define NCLS 201
#define KP 5
#define CKPAD 1024        // padded proto-row count (>=1005)
#define GSPLIT 16         // K-splits for G GEMM
#define PSPLIT 4          // row-splits for P_new

// ---------- kernels ----------

// canonicalize labels (int64 vs int32 layout; detection is deterministic)
__global__ void k_labels(const int* __restrict__ raw, int* __restrict__ lab){
  if (threadIdx.x == 0){
    bool is64 = true;
    for (int i=0;i<8;i++){
      int lo = raw[2*i], hi = raw[2*i+1];
      if (hi != 0 || lo < 0 || lo >= NCLS-1){ is64 = false; break; }
    }
    for (int i=0;i<32;i++) lab[i] = is64 ? raw[2*i] : raw[i];
  }
}

// init accumulators (re-run every call: idempotent)
__global__ void k_init(unsigned int* ipl_enc, int* cnt, int* cur, int* present,
                       unsigned int* minmax, float* meansum){
  int i = blockIdx.x*256 + threadIdx.x;
  if (i < 32*CKPAD) ipl_enc[i] = 0u;             // < any encoded real value
  if (i < NCLS){ cnt[i]=0; cur[i]=0; present[i]=0; }
  if (i < DIM) meansum[i] = 0.f;
  if (i == 0){ minmax[0]=0xFFFFFFFFu; minmax[1]=0u; }
}

// normalize prototypes -> bf16, zero-pad rows [1005,1024)
__global__ void k_proto(const float* __restrict__ protos, unsigned short* __restrict__ protn){
  int row = blockIdx.x;           // 0..1023
  int l = threadIdx.x;            // 64
  if (row >= NCLS*KP){
    for (int j=0;j<12;j++) protn[(size_t)row*DIM + l + j*64] = 0;
    return;
  }
  const float* p = protos + (size_t)row*DIM;
  float x[12]; float s = 0.f;
  for (int j=0;j<12;j++){ x[j] = p[l + j*64]; s += x[j]*x[j]; }
  s = waveSum(s);
  float inv = 1.0f / fmaxf(sqrtf(s), 1e-12f);
  for (int j=0;j<12;j++) protn[(size_t)row*DIM + l + j*64] = f2bf(x[j]*inv);
}

// column sums of X (for mean)
__global__ void k_mean(const float* __restrict__ X, float* __restrict__ meansum){
  int t = threadIdx.x;
  const float* base = X + (size_t)blockIdx.x*128*DIM;
  float a0=0.f, a1=0.f, a2=0.f;
  for (int r=0;r<128;r++){
    const float* row = base + (size_t)r*DIM;
    a0 += row[t]; a1 += row[t+256]; a2 += row[t+512];
  }
  atomicAdd(&meansum[t], a0);
  atomicAdd(&meansum[t+256], a1);
  atomicAdd(&meansum[t+512], a2);
}

// transpose X -> hiT/loT bf16 split, [DIM][BN_TOT]
__global__ void k_trans(const float* __restrict__ X, unsigned short* __restrict__ hiT,
                        unsigned short* __restrict__ loT){
  __shared__ float tile[64][65];
  int n0 = blockIdx.x*64, c0 = blockIdx.y*64;
  int t = threadIdx.x;
  for (int i=0;i<16;i++){
    int idx = t + i*256; int r = idx>>6, c = idx&63;
    tile[r][c] = X[(size_t)(n0+r)*DIM + c0+c];
  }
  __syncthreads();
  for (int i=0;i<16;i++){
    int idx = t + i*256; int c = idx>>6, n = idx&63;
    float x = tile[n][c];
    unsigned short h = f2bf(x);
    float hf = bf2f(h);
    unsigned short lo = f2bf(x - hf);
    size_t o = (size_t)(c0+c)*BN_TOT + n0+n;
    hiT[o] = h; loT[o] = lo;
  }
}

// row-normalize patch tokens -> bf16
__global__ void k_ptn(const float* __restrict__ X, unsigned short* __restrict__ ptn){
  int row = blockIdx.x*4 + (threadIdx.x>>6);
  int l = threadIdx.x & 63;
  const float* p = X + (size_t)row*DIM;
  float x[12]; float s = 0.f;
  for (int j=0;j<12;j++){ x[j] = p[l + j*64]; s += x[j]*x[j]; }
  s = waveSum(s);
  float inv = 1.0f / fmaxf(sqrtf(s), 1e-12f);
  for (int j=0;j<12;j++) ptn[(size_t)row*DIM + l + j*64] = f2bf(x[j]*inv);
}

// main logits GEMM with fused per-image column max
// XCD-chunked block remap: each XCD gets a contiguous mb range; the 8 nb
// blocks of one mb are adjacent on the same XCD -> A-panel L2-resident.
__global__ __launch_bounds__(256) void k_gemm_logits(const unsigned short* __restrict__ A,
                                                     const unsigned short* __restrict__ Bt,
                                                     unsigned int* __restrict__ ipl_enc){
  __shared__ __align__(16) unsigned short As[128][32];
  __shared__ __align__(16) unsigned short Bs[128][32];
  __shared__ float red[2][2][64];
  int flat = blockIdx.y*8 + blockIdx.x;   // gridDim = (8, 256)
  int xcd = flat & 7, j = flat >> 3;      // j in 0..255
  int mb = xcd*32 + (j>>3);
  int nb = j & 7;
  int t = threadIdx.x;
  int w = t>>6, l = t&63;
  int wr = w>>1, wc = w&1;
  f32x4 acc[4][4];
  #pragma unroll
  for (int m=0;m<4;m++)
    #pragma unroll
    for (int n=0;n<4;n++){ acc[m][n][0]=0.f; acc[m][n][1]=0.f; acc[m][n][2]=0.f; acc[m][n][3]=0.f; }

  for (int kt=0; kt<24; kt++){
    int k0 = kt*32;
    __syncthreads();
    #pragma unroll
    for (int i=0;i<2;i++){
      int ch = t + i*256;
      int r = ch>>2, co = (ch&3)*8;
      *(uint4*)&As[r][co] = *(const uint4*)&A[(size_t)(mb*128 + r)*DIM + k0 + co];
      *(uint4*)&Bs[r][co] = *(const uint4*)&Bt[(size_t)(nb*128 + r)*DIM + k0 + co];
    }
    __syncthreads();
    bf16x8 a[4], b[4];
    #pragma unroll
    for (int m=0;m<4;m++) a[m] = *(const bf16x8*)&As[wr*64 + m*16 + (l&15)][(l>>4)*8];
    #pragma unroll
    for (int n=0;n<4;n++) b[n] = *(const bf16x8*)&Bs[wc*64 + n*16 + (l&15)][(l>>4)*8];
    #pragma unroll
    for (int m=0;m<4;m++)
      #pragma unroll
      for (int n=0;n<4;n++)
        acc[m][n] = __builtin_amdgcn_mfma_f32_16x16x32_bf16(a[m], b[n], acc[m][n], 0,0,0);
  }
  // per-column max over this block's 128 rows
  float vmax[4];
  #pragma unroll
  for (int n=0;n<4;n++){
    float v = -1e30f;
    #pragma unroll
    for (int m=0;m<4;m++)
      #pragma unroll
      for (int r=0;r<4;r++) v = fmaxf(v, acc[m][n][r]);
    v = fmaxf(v, __shfl_xor(v, 16, 64));
    v = fmaxf(v, __shfl_xor(v, 32, 64));
    vmax[n] = v;
  }
  __syncthreads();
  if (l < 16){
    #pragma unroll
    for (int n=0;n<4;n++) red[wc][wr][n*16 + l] = vmax[n];
  }
  __syncthreads();
  if (t < 128){
    int wcc = t>>6, col = t&63;
    float v = fmaxf(red[wcc][0][col], red[wcc][1][col]);
    int gcol = nb*128 + wcc*64 + col;
    if (gcol < NCLS*KP){
      int b = (mb*128) >> 10;
      atomicMax(&ipl_enc[b*CKPAD + gcol], fenc(v));
    }
  }
}

// G split-bf16 GEMM, SYMMETRIC: only upper-tri tile pairs (ib<=jb), mirrored
// stores. Gpart[s] tile = hi^T hi + hi^T lo + lo^T hi  (K chunk 2048)
__global__ __launch_bounds__(256) void k_gemm_G(const unsigned short* __restrict__ hiT,
                                                const unsigned short* __restrict__ loT,
                                                float* __restrict__ Gpart){
  __shared__ __align__(16) unsigned short Ahi[128][32];
  __shared__ __align__(16) unsigned short Alo[128][32];
  __shared__ __align__(16) unsigned short Bhi[128][32];
  __shared__ __align__(16) unsigned short Blo[128][32];
  // pair index -> (ib, jb), ib <= jb, 6x6 tiles -> 21 pairs
  int p = blockIdx.x;
  int ib = 0, rem = p;
  while (rem >= 6 - ib){ rem -= 6 - ib; ib++; }
  int jb = ib + rem;
  int s = blockIdx.y;
  int t = threadIdx.x, w = t>>6, l = t&63, wr = w>>1, wc = w&1;
  f32x4 acc[4][4];
  #pragma unroll
  for (int m=0;m<4;m++)
    #pragma unroll
    for (int n=0;n<4;n++){ acc[m][n][0]=0.f; acc[m][n][1]=0.f; acc[m][n][2]=0.f; acc[m][n][3]=0.f; }

  for (int kt=0; kt<64; kt++){
    size_t k0 = (size_t)s*2048 + (size_t)kt*32;
    __syncthreads();
    #pragma unroll
    for (int i=0;i<2;i++){
      int ch = t + i*256; int r = ch>>2, co = (ch&3)*8;
      size_t ga = (size_t)(ib*128 + r)*BN_TOT + k0 + co;
      size_t gb = (size_t)(jb*128 + r)*BN_TOT + k0 + co;
      *(uint4*)&Ahi[r][co] = *(const uint4*)&hiT[ga];
      *(uint4*)&Alo[r][co] = *(const uint4*)&loT[ga];
      *(uint4*)&Bhi[r][co] = *(const uint4*)&hiT[gb];
      *(uint4*)&Blo[r][co] = *(const uint4*)&loT[gb];
    }
    __syncthreads();
    bf16x8 ah[4], al[4], bh[4], bl[4];
    #pragma unroll
    for (int m=0;m<4;m++){
      ah[m] = *(const bf16x8*)&Ahi[wr*64 + m*16 + (l&15)][(l>>4)*8];
      al[m] = *(const bf16x8*)&Alo[wr*64 + m*16 + (l&15)][(l>>4)*8];
    }
    #pragma unroll
    for (int n=0;n<4;n++){
      bh[n] = *(const bf16x8*)&Bhi[wc*64 + n*16 + (l&15)][(l>>4)*8];
      bl[n] = *(const bf16x8*)&Blo[wc*64 + n*16 + (l&15)][(l>>4)*8];
    }
    #pragma unroll
    for (int m=0;m<4;m++)
      #pragma unroll
      for (int n=0;n<4;n++){
        acc[m][n] = __builtin_amdgcn_mfma_f32_16x16x32_bf16(ah[m], bh[n], acc[m][n], 0,0,0);
        acc[m][n] = __builtin_amdgcn_mfma_f32_16x16x32_bf16(ah[m], bl[n], acc[m][n], 0,0,0);
        acc[m][n] = __builtin_amdgcn_mfma_f32_16x16x32_bf16(al[m], bh[n], acc[m][n], 0,0,0);
      }
  }
  float* out = Gpart + (size_t)s*DIM*DIM;
  #pragma unroll
  for (int m=0;m<4;m++)
    #pragma unroll
    for (int n=0;n<4;n++)
      #pragma unroll
      for (int r=0;r<4;r++){
        int row = ib*128 + wr*64 + m*16 + (l>>4)*4 + r;
        int col = jb*128 + wc*64 + n*16 + (l&15);
        out[(size_t)row*DIM + col] = acc[m][n][r];
        if (ib != jb) out[(size_t)col*DIM + row] = acc[m][n][r];
      }
}

// G' = sum(Gpart)/N - mu mu^T
__global__ void k_gfix(const float* __restrict__ Gpart, const float* __restrict__ meansum,
                       float* __restrict__ G){
  int i = blockIdx.x*256 + threadIdx.x;   // < 768*768 exactly
  int r = i/DIM, c = i%DIM;
  float s = 0.f;
  #pragma unroll
  for (int p=0;p<GSPLIT;p++) s += Gpart[(size_t)p*DIM*DIM + i];
  const float invN = 1.0f/32768.0f;
  float mr = meansum[r]*invN, mc = meansum[c]*invN;
  G[i] = s*invN - mr*mc;
}

// v0 = jax.random.normal(key(1), (768,)) — PARTITIONABLE threefry path
__global__ void k_v0(float* __restrict__ v){
  int i = blockIdx.x*256 + threadIdx.x;
  if (i >= DIM) return;
  unsigned int ks[3] = {0u, 1u, 0x1BD11BDBu};   // 0 ^ 1 ^ 0x1BD11BDA
  const int rot0[4] = {13,15,26,6};
  const int rot1[4] = {17,29,16,24};
  unsigned int x0 = 0u, x1 = (unsigned int)i;
  x0 += ks[0]; x1 += ks[1];
  #pragma unroll
  for (int g=0; g<5; g++){
    const int* rr = (g&1) ? rot1 : rot0;
    #pragma unroll
    for (int j=0;j<4;j++){
      x0 += x1;
      x1 = (x1 << rr[j]) | (x1 >> (32-rr[j]));
      x1 ^= x0;
    }
    x0 += ks[(g+1)%3];
    x1 += ks[(g+2)%3] + (unsigned int)(g+1);
  }
  unsigned int b = x0 ^ x1;
  const float lo = __uint_as_float(0xBF7FFFFFu);      // nextafter(-1,0)
  const float sq2 = __uint_as_float(0x3FB504F3u);     // sqrt(2) f32
  float f = __uint_as_float((b>>9) | 0x3F800000u) - 1.0f;
  float u = __fadd_rn(__fmul_rn(f, 2.0f), lo);
  u = fmaxf(lo, u);
  v[i] = sq2 * erfinv_f(u);
}

// v_out = G * v_in   (one wave per row)
__global__ void k_mv(const float* __restrict__ G, const float* __restrict__ vin,
                     float* __restrict__ vout){
  __shared__ float vs[DIM];
  int t = threadIdx.x;
  for (int i=t;i<DIM;i+=256) vs[i] = vin[i];
  __syncthreads();
  int row = blockIdx.x*4 + (t>>6), l = t&63;
  const float* g = G + (size_t)row*DIM;
  float s = 0.f;
  for (int j=0;j<12;j++) s += g[l + j*64]*vs[l + j*64];
  s = waveSum(s);
  if (l==0) vout[row] = s;
}

// scal[0] = mu . v
__global__ void k_muv(const float* __restrict__ meansum, const float* __restrict__ v,
                      float* __restrict__ scal){
  __shared__ float red[256];
  int t = threadIdx.x;
  float s = 0.f;
  for (int i=t;i<DIM;i+=256) s += meansum[i]*(1.0f/32768.0f)*v[i];
  float r = blockSum(s, red);
  if (t==0) scal[0] = r;
}

// u[n] = X[n,:].v - mu.v
__global__ void k_u(const unsigned short* __restrict__ hiT, const unsigned short* __restrict__ loT,
                    const float* __restrict__ v, const float* __restrict__ scal,
                    float* __restrict__ u){
  __shared__ float vs[DIM];
  int t = threadIdx.x;
  for (int i=t;i<DIM;i+=256) vs[i] = v[i];
  __syncthreads();
  size_t n = (size_t)blockIdx.x*256 + t;
  float acc = 0.f;
  for (int c=0;c<DIM;c++){
    size_t o = (size_t)c*BN_TOT + n;
    acc += (bf2f(hiT[o]) + bf2f(loT[o])) * vs[c];
  }
  u[n] = acc - scal[0];
}

__global__ void k_minmax(const float* __restrict__ u, unsigned int* __restrict__ minmax){
  int i = blockIdx.x*256 + threadIdx.x;
  float x = u[i];
  float mn = x, mx = x;
  for (int m=32;m;m>>=1){
    mn = fminf(mn, __shfl_xor(mn, m, 64));
    mx = fmaxf(mx, __shfl_xor(mx, m, 64));
  }
  __shared__ float smn[4], smx[4];
  int w = threadIdx.x>>6;
  if ((threadIdx.x&63)==0){ smn[w]=mn; smx[w]=mx; }
  __syncthreads();
  if (threadIdx.x==0){
    for (int k=1;k<4;k++){ mn = fminf(mn, smn[k]); mx = fmaxf(mx, smx[k]); }
    atomicMin(&minmax[0], fenc(mn));
    atomicMax(&minmax[1], fenc(mx));
  }
}

// patch labels + per-class counts (fg only)
__global__ void k_pl(const float* __restrict__ u, const int* __restrict__ labels,
                     const unsigned int* __restrict__ minmax, int* __restrict__ pl,
                     int* __restrict__ cnt){
  int n = blockIdx.x*256 + threadIdx.x;
  float umin = fdec(minmax[0]), umax = fdec(minmax[1]);
  float us = (u[n]-umin)/(umax-umin);
  int c = (us < 0.5f) ? labels[n>>10] : (NCLS-1);
  pl[n] = c;
  if (c < NCLS-1) atomicAdd(&cnt[c], 1);
}

// prefix offsets + present bitmap
__global__ void k_offs(const int* __restrict__ cnt, int* __restrict__ offs,
                       const int* __restrict__ labels, int* __restrict__ present){
  if (threadIdx.x == 0){
    int acc = 0;
    for (int c=0;c<NCLS-1;c++){ offs[c] = acc; acc += cnt[c]; }
    offs[NCLS-1] = acc;
  }
  if (threadIdx.x < 32) atomicOr(&present[labels[threadIdx.x]], 1);
}

__global__ void k_scatter(const int* __restrict__ pl, const int* __restrict__ offs,
                          int* __restrict__ cur, int* __restrict__ idx){
  int n = blockIdx.x*256 + threadIdx.x;
  int c = pl[n];
  if (c < NCLS-1){
    int p = offs[c] + atomicAdd(&cur[c], 1);
    idx[p] = n;
  }
}

// own-class logits -> q0 = exp(L/eps), stored in class-sorted order
__global__ void k_qlog(const int* __restrict__ idx, const int* __restrict__ offs,
                       const int* __restrict__ pl, const unsigned short* __restrict__ ptn,
                       const unsigned short* __restrict__ protn, float* __restrict__ q){
  int i = blockIdx.x*4 + (threadIdx.x>>6);
  int l = threadIdx.x & 63;
  int total = offs[NCLS-1];
  if (i >= total) return;
  int n = idx[i];
  int c = pl[n];
  const unsigned short* pr = ptn + (size_t)n*DIM;
  float x[12];
  for (int j=0;j<12;j++) x[j] = bf2f(pr[l + j*64]);
  for (int k=0;k<KP;k++){
    const unsigned short* wv = protn + (size_t)(c*KP + k)*DIM;
    float s = 0.f;
    for (int j=0;j<12;j++) s += x[j]*bf2f(wv[l + j*64]);
    s = waveSum(s);
    if (l==0) q[(size_t)i*KP + k] = expf(s*20.0f);
  }
}

// per-class sinkhorn in place on its sorted segment
__global__ void k_sink(const int* __restrict__ cnt, const int* __restrict__ offs,
                       float* __restrict__ q){
  __shared__ float red[256];
  __shared__ float colf[KP];
  int c = blockIdx.x;
  int nc = cnt[c];
  if (nc == 0) return;
  int n0 = offs[c];
  float* Q = q + (size_t)n0*KP;
  int t = threadIdx.x;
  int tot5 = nc*KP;
  float s = 0.f;
  for (int i=t;i<tot5;i+=256) s += Q[i];
  float total = blockSum(s, red);
  float sc = 1.0f/fmaxf(total, 1e-9f);
  for (int i=t;i<tot5;i+=256) Q[i] *= sc;
  __syncthreads();
  float ncf = (float)nc;
  for (int it=0; it<3; it++){
    float cs[KP] = {0,0,0,0,0};
    for (int i=t;i<nc;i+=256){
      const float* row = Q + (size_t)i*KP;
      #pragma unroll
      for (int k=0;k<KP;k++) cs[k] += row[k];
    }
    for (int k=0;k<KP;k++){
      float v = blockSum(cs[k], red);
      if (t==0) colf[k] = 1.0f/(fmaxf(v,1e-9f)*(float)KP);
    }
    __syncthreads();
    for (int i=t;i<nc;i+=256){
      float* row = Q + (size_t)i*KP;
      float qq[KP]; float rs = 0.f;
      #pragma unroll
      for (int k=0;k<KP;k++){ qq[k] = row[k]*colf[k]; rs += qq[k]; }
      float rf = 1.0f/(fmaxf(rs,1e-9f)*ncf);
      #pragma unroll
      for (int k=0;k<KP;k++) row[k] = qq[k]*rf;
    }
    __syncthreads();
  }
  for (int i=t;i<tot5;i+=256) Q[i] *= ncf;
}

// P4[s][c][k][d] = partial sum over this split's class-c rows of Q[n,k]*ptn[n,d]
// one block per (split, class); 256 threads each own 3 of 768 dims.
__global__ void k_pnew(const int* __restrict__ cnt, const int* __restrict__ offs,
                       const int* __restrict__ present, const int* __restrict__ idx,
                       const float* __restrict__ q, const unsigned short* __restrict__ ptn,
                       float* __restrict__ P4){
  int c = blockIdx.y, s = blockIdx.x;
  if (!present[c]) return;
  int nc = cnt[c], n0 = offs[c];
  int r0 = n0 + (nc*s)/PSPLIT;
  int r1 = n0 + (nc*(s+1))/PSPLIT;
  int t = threadIdx.x;
  float acc[KP][3];
  #pragma unroll
  for (int k=0;k<KP;k++){ acc[k][0]=0.f; acc[k][1]=0.f; acc[k][2]=0.f; }
  for (int i=r0; i<r1; ++i){
    int n = idx[i];
    float qv[KP];
    #pragma unroll
    for (int k=0;k<KP;k++) qv[k] = q[(size_t)i*KP + k];
    const unsigned short* row = ptn + (size_t)n*DIM;
    #pragma unroll
    for (int j=0;j<3;j++){
      float x = bf2f(row[t + j*256]);
      #pragma unroll
      for (int k=0;k<KP;k++) acc[k][j] += qv[k]*x;
    }
  }
  float* out = P4 + ((size_t)(s*NCLS + c)*KP)*DIM;
  #pragma unroll
  for (int k=0;k<KP;k++)
    #pragma unroll
    for (int j=0;j<3;j++)
      out[(size_t)k*DIM + t + j*256] = acc[k][j];
}

// new_prototypes = present ? 0.9*p + 0.1*sum_s(P4[s]) : p
__global__ void k_ema(const float* __restrict__ protos, const float* __restrict__ P4,
                      const int* __restrict__ present, float* __restrict__ out){
  int i = blockIdx.x*256 + threadIdx.x;
  if (i >= NCLS*KP*DIM) return;
  int c = i / (KP*DIM);
  float p = protos[i];
  if (present[c]){
    float s = 0.f;
    #pragma unroll
    for (int sp=0; sp<PSPLIT; sp++) s += P4[(size_t)sp*NCLS*KP*DIM + i];
    out[i] = 0.9f*p + 0.1f*s;
  } else {
    out[i] = p;
  }
}

// decode ipl + class_logits
__global__ void k_final(const unsigned int* __restrict__ ipl_enc, float* __restrict__ out){
  int i = blockIdx.x*256 + threadIdx.x;
  if (i < 32*NCLS*KP){
    int b = i / (NCLS*KP), ck = i % (NCLS*KP);
    out[32*NCLS + i] = fdec(ipl_enc[b*CKPAD + ck]);
  }
  if (i < 32*NCLS){
    int b = i / NCLS, c = i % NCLS;
    float s = 0.f;
    #pragma unroll
    for (int k=0;k<KP;k++) s += fdec(ipl_enc[b*CKPAD + c*KP + k]);
    out[b*NCLS + c] = s;
  }
}

// ---------- launch ----------
extern "C" void kernel_launch(void* const* d_in, const int* in_sizes, int n_in,
                              void* d_out, int out_size, void* d_ws, size_t ws_size,
                              hipStream_t stream){
  (void)in_sizes; (void)n_in; (void)out_size; (void)ws_size;
  const float* X = (const float*)d_in[0];
  const float* protos = (const float*)d_in[1];
  const int* labels_raw = (const int*)d_in[2];
  float* out = (float*)d_out;

  char* w = (char*)d_ws;
  size_t off = 0;
  auto alloc = [&](size_t bytes)->void*{
    void* p = (void*)(w + off);
    off = (off + bytes + 255) & ~(size_t)255;
    return p;
  };
  unsigned short* hiT   = (unsigned short*)alloc((size_t)DIM*BN_TOT*2);
  unsigned short* loT   = (unsigned short*)alloc((size_t)DIM*BN_TOT*2);
  unsigned short* ptn   = (unsigned short*)alloc((size_t)BN_TOT*DIM*2);
  unsigned short* protn = (unsigned short*)alloc((size_t)CKPAD*DIM*2);
  float* Gpart   = (float*)alloc((size_t)GSPLIT*DIM*DIM*4);
  float* G       = (float*)alloc((size_t)DIM*DIM*4);
  float* meansum = (float*)alloc(DIM*4);
  float* vA      = (float*)alloc(DIM*4);
  float* vB      = (float*)alloc(DIM*4);
  float* scal    = (float*)alloc(256);
  float* u       = (float*)alloc(BN_TOT*4);
  int* pl        = (int*)alloc(BN_TOT*4);
  int* idx       = (int*)alloc(BN_TOT*4);
  float* q       = (float*)alloc((size_t)BN_TOT*KP*4);
  int* cnt       = (int*)alloc(1024);
  int* cur       = (int*)alloc(1024);
  int* offs      = (int*)alloc(1024);
  int* present   = (int*)alloc(1024);
  int* labc      = (int*)alloc(256);
  unsigned int* minmax  = (unsigned int*)alloc(256);
  unsigned int* ipl_enc = (unsigned int*)alloc((size_t)32*CKPAD*4);
  float* P4      = (float*)alloc((size_t)PSPLIT*NCLS*KP*DIM*4);

  dim3 b256(256);
  k_labels<<<dim3(1), dim3(64), 0, stream>>>(labels_raw, labc);
  k_init<<<dim3(128), b256, 0, stream>>>(ipl_enc, cnt, cur, present, minmax, meansum);
  k_proto<<<dim3(CKPAD), dim3(64), 0, stream>>>(protos, protn);
  k_mean<<<dim3(256), b256, 0, stream>>>(X, meansum);
  k_trans<<<dim3(512,12), b256, 0, stream>>>(X, hiT, loT);
  k_ptn<<<dim3(8192), b256, 0, stream>>>(X, ptn);
  k_gemm_logits<<<dim3(8,256), b256, 0, stream>>>(ptn, protn, ipl_enc);
  k_gemm_G<<<dim3(21,GSPLIT), b256, 0, stream>>>(hiT, loT, Gpart);
  k_gfix<<<dim3(2304), b256, 0, stream>>>(Gpart, meansum, G);
  k_v0<<<dim3(3), b256, 0, stream>>>(vA);
  for (int it=0; it<10; it++){
    float* src = (it&1) ? vB : vA;
    float* dst = (it&1) ? vA : vB;
    k_mv<<<dim3(192), b256, 0, stream>>>(G, src, dst);
  }
  k_muv<<<dim3(1), b256, 0, stream>>>(meansum, vA, scal);
  k_u<<<dim3(128), b256, 0, stream>>>(hiT, loT, vA, scal, u);
  k_minmax<<<dim3(128), b256, 0, stream>>>(u, minmax);
  k_pl<<<dim3(128), b256, 0, stream>>>(u, labc, minmax, pl, cnt);
  k_offs<<<dim3(1), b256, 0, stream>>>(cnt, offs, labc, present);
  k_scatter<<<dim3(128), b256, 0, stream>>>(pl, offs, cur, idx);
  k_qlog<<<dim3(8192), b256, 0, stream>>>(idx, offs, pl, ptn, protn, q);
  k_sink<<<dim3(200), b256, 0, stream>>>(cnt, offs, q);
  k_pnew<<<dim3(PSPLIT,NCLS), b256, 0, stream>>>(cnt, offs, present, idx, q, ptn, P4);
  k_ema<<<dim3(3015), b256, 0, stream>>>(protos, P4, present, out + 32*NCLS + 32*NCLS*KP);
  k_final<<<dim3(126), b256, 0, stream>>>(ipl_enc, out);
}

// Round 5
// 528.326 us; speedup vs baseline: 1.5190x; 1.0919x over previous
//
#include <hip/hip_runtime.h>
#include <stdint.h>
#include <stddef.h>

#define DEV static __device__ __forceinline__

typedef __attribute__((ext_vector_type(8))) short bf16x8;
typedef __attribute__((ext_vector_type(4))) float f32x4;

// ---------- small helpers ----------
DEV float bf2f(unsigned short u){ union{unsigned int i; float f;} v; v.i = ((unsigned int)u)<<16; return v.f; }
DEV unsigned short f2bf(float f){ union{float f; unsigned int i;} v; v.f=f; unsigned int i=v.i;
  return (unsigned short)((i + 0x7FFFu + ((i>>16)&1u)) >> 16); }
// monotone float<->uint encoding for atomic min/max
DEV unsigned int fenc(float x){ unsigned int i = __float_as_uint(x); return (i & 0x80000000u) ? ~i : (i | 0x80000000u); }
DEV float fdec(unsigned int e){ unsigned int i = (e & 0x80000000u) ? (e & 0x7FFFFFFFu) : ~e; return __uint_as_float(i); }

DEV float waveSum(float s){
  for (int m=32;m;m>>=1) s += __shfl_xor(s, m, 64);
  return s;
}

DEV float blockSum(float v, float* red){
  int t = threadIdx.x;
  red[t] = v; __syncthreads();
  for (int k=128;k>0;k>>=1){ if (t<k) red[t] += red[t+k]; __syncthreads(); }
  float r = red[0]; __syncthreads();
  return r;
}

// XLA ErfInv32 (Giles polynomial, log1p variant)
DEV float erfinv_f(float x){
  float w = -log1pf(-__fmul_rn(x,x));
  float p;
  if (w < 5.0f){
    w = w - 2.5f;
    p = 2.81022636e-08f;
    p = 3.43273939e-07f + p*w;
    p = -3.5233877e-06f + p*w;
    p = -4.39150654e-06f + p*w;
    p = 0.00021858087f + p*w;
    p = -0.00125372503f + p*w;
    p = -0.00417768164f + p*w;
    p = 0.246640727f + p*w;
    p = 1.50140941f + p*w;
  } else {
    w = sqrtf(w) - 3.0f;
    p = -0.000200214257f;
    p = 0.000100950558f + p*w;
    p = 0.00134934322f + p*w;
    p = -0.00367342844f + p*w;
    p = 0.00573950773f + p*w;
    p = -0.0076224613f + p*w;
    p = 0.00943887047f + p*w;
    p = 1.00167406f + p*w;
    p = 2.83297682f + p*w;
  }
  return p*x;
}

// ---------- constants ----------
#define BN_TOT 32768      // B*n_patches
#define DIM 768
#define NCLS 201
#define KP 5
#define CKPAD 1024        // padded proto-row count (>=1005)
#define GSPLIT 32         // K-splits for G GEMM
#define PSPLIT 8          // row-splits for P_new
#define LPAD 40           // padded LDS row (shorts): 80B stride, 16B-aligned, bank-spread

// ---------- kernels ----------

// fused setup: init accumulators + canonicalize labels + v0 (threefry partitionable)
__global__ void k_setup(unsigned int* ipl_enc, int* cnt, int* cur, int* present,
                        unsigned int* minmax, float* meansum,
                        const int* __restrict__ raw, int* __restrict__ lab,
                        float* __restrict__ v){
  int i = blockIdx.x*256 + threadIdx.x;   // exactly 32768 threads
  ipl_enc[i] = 0u;
  if (i < NCLS){ cnt[i]=0; cur[i]=0; present[i]=0; }
  if (i < DIM) meansum[i] = 0.f;
  if (i == 0){
    minmax[0]=0xFFFFFFFFu; minmax[1]=0u;
    // labels: int64 vs int32 layout detection (deterministic)
    bool is64 = true;
    for (int j=0;j<8;j++){
      int lo = raw[2*j], hi = raw[2*j+1];
      if (hi != 0 || lo < 0 || lo >= NCLS-1){ is64 = false; break; }
    }
    for (int j=0;j<32;j++) lab[j] = is64 ? raw[2*j] : raw[j];
  }
  if (i < DIM){
    unsigned int ks[3] = {0u, 1u, 0x1BD11BDBu};   // 0 ^ 1 ^ 0x1BD11BDA
    const int rot0[4] = {13,15,26,6};
    const int rot1[4] = {17,29,16,24};
    unsigned int x0 = 0u, x1 = (unsigned int)i;
    x0 += ks[0]; x1 += ks[1];
    #pragma unroll
    for (int g=0; g<5; g++){
      const int* rr = (g&1) ? rot1 : rot0;
      #pragma unroll
      for (int j=0;j<4;j++){
        x0 += x1;
        x1 = (x1 << rr[j]) | (x1 >> (32-rr[j]));
        x1 ^= x0;
      }
      x0 += ks[(g+1)%3];
      x1 += ks[(g+2)%3] + (unsigned int)(g+1);
    }
    unsigned int b = x0 ^ x1;
    const float lo = __uint_as_float(0xBF7FFFFFu);      // nextafter(-1,0)
    const float sq2 = __uint_as_float(0x3FB504F3u);     // sqrt(2) f32
    float f = __uint_as_float((b>>9) | 0x3F800000u) - 1.0f;
    float uu = __fadd_rn(__fmul_rn(f, 2.0f), lo);
    uu = fmaxf(lo, uu);
    v[i] = sq2 * erfinv_f(uu);
  }
}

// normalize prototypes -> bf16, zero-pad rows [1005,1024)
__global__ void k_proto(const float* __restrict__ protos, unsigned short* __restrict__ protn){
  int row = blockIdx.x;           // 0..1023
  int l = threadIdx.x;            // 64
  if (row >= NCLS*KP){
    for (int j=0;j<12;j++) protn[(size_t)row*DIM + l + j*64] = 0;
    return;
  }
  const float* p = protos + (size_t)row*DIM;
  float x[12]; float s = 0.f;
  for (int j=0;j<12;j++){ x[j] = p[l + j*64]; s += x[j]*x[j]; }
  s = waveSum(s);
  float inv = 1.0f / fmaxf(sqrtf(s), 1e-12f);
  for (int j=0;j<12;j++) protn[(size_t)row*DIM + l + j*64] = f2bf(x[j]*inv);
}

// transpose X -> hiT/loT bf16 split, [DIM][BN_TOT]; fused column sums (mean)
__global__ void k_trans(const float* __restrict__ X, unsigned short* __restrict__ hiT,
                        unsigned short* __restrict__ loT, float* __restrict__ meansum){
  __shared__ float tile[64][65];
  __shared__ float colsum[4][64];
  int n0 = blockIdx.x*64, c0 = blockIdx.y*64;
  int t = threadIdx.x;
  float part = 0.f;
  for (int i=0;i<16;i++){
    int idx = t + i*256; int r = idx>>6, c = idx&63;
    float x = X[(size_t)(n0+r)*DIM + c0+c];
    tile[r][c] = x;
    part += x;
  }
  colsum[t>>6][t&63] = part;
  __syncthreads();
  for (int i=0;i<16;i++){
    int idx = t + i*256; int c = idx>>6, n = idx&63;
    float x = tile[n][c];
    unsigned short h = f2bf(x);
    float hf = bf2f(h);
    unsigned short lo = f2bf(x - hf);
    size_t o = (size_t)(c0+c)*BN_TOT + n0+n;
    hiT[o] = h; loT[o] = lo;
  }
  if (t < 64){
    float s = colsum[0][t]+colsum[1][t]+colsum[2][t]+colsum[3][t];
    atomicAdd(&meansum[c0+t], s);
  }
}

// row-normalize patch tokens -> bf16
__global__ void k_ptn(const float* __restrict__ X, unsigned short* __restrict__ ptn){
  int row = blockIdx.x*4 + (threadIdx.x>>6);
  int l = threadIdx.x & 63;
  const float* p = X + (size_t)row*DIM;
  float x[12]; float s = 0.f;
  for (int j=0;j<12;j++){ x[j] = p[l + j*64]; s += x[j]*x[j]; }
  s = waveSum(s);
  float inv = 1.0f / fmaxf(sqrtf(s), 1e-12f);
  for (int j=0;j<12;j++) ptn[(size_t)row*DIM + l + j*64] = f2bf(x[j]*inv);
}

// main logits GEMM with fused per-image column max (XCD-chunked remap, padded LDS)
__global__ __launch_bounds__(256) void k_gemm_logits(const unsigned short* __restrict__ A,
                                                     const unsigned short* __restrict__ Bt,
                                                     unsigned int* __restrict__ ipl_enc){
  __shared__ __align__(16) unsigned short As[128][LPAD];
  __shared__ __align__(16) unsigned short Bs[128][LPAD];
  __shared__ float red[2][2][64];
  int flat = blockIdx.y*8 + blockIdx.x;   // gridDim = (8, 256)
  int xcd = flat & 7, j = flat >> 3;      // j in 0..255
  int mb = xcd*32 + (j>>3);
  int nb = j & 7;
  int t = threadIdx.x;
  int w = t>>6, l = t&63;
  int wr = w>>1, wc = w&1;
  f32x4 acc[4][4];
  #pragma unroll
  for (int m=0;m<4;m++)
    #pragma unroll
    for (int n=0;n<4;n++){ acc[m][n][0]=0.f; acc[m][n][1]=0.f; acc[m][n][2]=0.f; acc[m][n][3]=0.f; }

  for (int kt=0; kt<24; kt++){
    int k0 = kt*32;
    __syncthreads();
    #pragma unroll
    for (int i=0;i<2;i++){
      int ch = t + i*256;
      int r = ch>>2, co = (ch&3)*8;
      *(uint4*)&As[r][co] = *(const uint4*)&A[(size_t)(mb*128 + r)*DIM + k0 + co];
      *(uint4*)&Bs[r][co] = *(const uint4*)&Bt[(size_t)(nb*128 + r)*DIM + k0 + co];
    }
    __syncthreads();
    bf16x8 a[4], b[4];
    #pragma unroll
    for (int m=0;m<4;m++) a[m] = *(const bf16x8*)&As[wr*64 + m*16 + (l&15)][(l>>4)*8];
    #pragma unroll
    for (int n=0;n<4;n++) b[n] = *(const bf16x8*)&Bs[wc*64 + n*16 + (l&15)][(l>>4)*8];
    #pragma unroll
    for (int m=0;m<4;m++)
      #pragma unroll
      for (int n=0;n<4;n++)
        acc[m][n] = __builtin_amdgcn_mfma_f32_16x16x32_bf16(a[m], b[n], acc[m][n], 0,0,0);
  }
  // per-column max over this block's 128 rows
  float vmax[4];
  #pragma unroll
  for (int n=0;n<4;n++){
    float v = -1e30f;
    #pragma unroll
    for (int m=0;m<4;m++)
      #pragma unroll
      for (int r=0;r<4;r++) v = fmaxf(v, acc[m][n][r]);
    v = fmaxf(v, __shfl_xor(v, 16, 64));
    v = fmaxf(v, __shfl_xor(v, 32, 64));
    vmax[n] = v;
  }
  __syncthreads();
  if (l < 16){
    #pragma unroll
    for (int n=0;n<4;n++) red[wc][wr][n*16 + l] = vmax[n];
  }
  __syncthreads();
  if (t < 128){
    int wcc = t>>6, col = t&63;
    float v = fmaxf(red[wcc][0][col], red[wcc][1][col]);
    int gcol = nb*128 + wcc*64 + col;
    if (gcol < NCLS*KP){
      int b = (mb*128) >> 10;
      atomicMax(&ipl_enc[b*CKPAD + gcol], fenc(v));
    }
  }
}

// G split-bf16 GEMM, SYMMETRIC upper-tri pairs, XCD split-grouped remap,
// padded LDS. Gpart[s] tile = hi^T hi + hi^T lo + lo^T hi  (K chunk 1024)
__global__ __launch_bounds__(256) void k_gemm_G(const unsigned short* __restrict__ hiT,
                                                const unsigned short* __restrict__ loT,
                                                float* __restrict__ Gpart){
  __shared__ __align__(16) unsigned short Ahi[128][LPAD];
  __shared__ __align__(16) unsigned short Alo[128][LPAD];
  __shared__ __align__(16) unsigned short Bhi[128][LPAD];
  __shared__ __align__(16) unsigned short Blo[128][LPAD];
  // 672 blocks = 8 xcd x 4 split-groups x 21 pairs; split s -> xcd s%8 so the
  // 21 pair-blocks of one split share six 128-row panels (3.1MB) in that L2.
  int b = blockIdx.x;
  int xcd = b & 7, q = b >> 3;            // q in 0..83
  int s = xcd + 8*(q/21);                 // K-split 0..31
  int p = q % 21;
  int ib = 0, rem = p;
  while (rem >= 6 - ib){ rem -= 6 - ib; ib++; }
  int jb = ib + rem;
  int t = threadIdx.x, w = t>>6, l = t&63, wr = w>>1, wc = w&1;
  f32x4 acc[4][4];
  #pragma unroll
  for (int m=0;m<4;m++)
    #pragma unroll
    for (int n=0;n<4;n++){ acc[m][n][0]=0.f; acc[m][n][1]=0.f; acc[m][n][2]=0.f; acc[m][n][3]=0.f; }

  for (int kt=0; kt<32; kt++){
    size_t k0 = (size_t)s*1024 + (size_t)kt*32;
    __syncthreads();
    #pragma unroll
    for (int i=0;i<2;i++){
      int ch = t + i*256; int r = ch>>2, co = (ch&3)*8;
      size_t ga = (size_t)(ib*128 + r)*BN_TOT + k0 + co;
      size_t gb = (size_t)(jb*128 + r)*BN_TOT + k0 + co;
      *(uint4*)&Ahi[r][co] = *(const uint4*)&hiT[ga];
      *(uint4*)&Alo[r][co] = *(const uint4*)&loT[ga];
      *(uint4*)&Bhi[r][co] = *(const uint4*)&hiT[gb];
      *(uint4*)&Blo[r][co] = *(const uint4*)&loT[gb];
    }
    __syncthreads();
    bf16x8 ah[4], al[4], bh[4], bl[4];
    #pragma unroll
    for (int m=0;m<4;m++){
      ah[m] = *(const bf16x8*)&Ahi[wr*64 + m*16 + (l&15)][(l>>4)*8];
      al[m] = *(const bf16x8*)&Alo[wr*64 + m*16 + (l&15)][(l>>4)*8];
    }
    #pragma unroll
    for (int n=0;n<4;n++){
      bh[n] = *(const bf16x8*)&Bhi[wc*64 + n*16 + (l&15)][(l>>4)*8];
      bl[n] = *(const bf16x8*)&Blo[wc*64 + n*16 + (l&15)][(l>>4)*8];
    }
    #pragma unroll
    for (int m=0;m<4;m++)
      #pragma unroll
      for (int n=0;n<4;n++){
        acc[m][n] = __builtin_amdgcn_mfma_f32_16x16x32_bf16(ah[m], bh[n], acc[m][n], 0,0,0);
        acc[m][n] = __builtin_amdgcn_mfma_f32_16x16x32_bf16(ah[m], bl[n], acc[m][n], 0,0,0);
        acc[m][n] = __builtin_amdgcn_mfma_f32_16x16x32_bf16(al[m], bh[n], acc[m][n], 0,0,0);
      }
  }
  float* out = Gpart + (size_t)s*DIM*DIM;
  #pragma unroll
  for (int m=0;m<4;m++)
    #pragma unroll
    for (int n=0;n<4;n++)
      #pragma unroll
      for (int r=0;r<4;r++){
        int row = ib*128 + wr*64 + m*16 + (l>>4)*4 + r;
        int col = jb*128 + wc*64 + n*16 + (l&15);
        out[(size_t)row*DIM + col] = acc[m][n][r];
        if (ib != jb) out[(size_t)col*DIM + row] = acc[m][n][r];
      }
}

// G' = sum(Gpart)/N - mu mu^T
__global__ void k_gfix(const float* __restrict__ Gpart, const float* __restrict__ meansum,
                       float* __restrict__ G){
  int i = blockIdx.x*256 + threadIdx.x;   // < 768*768 exactly
  int r = i/DIM, c = i%DIM;
  float s = 0.f;
  for (int p=0;p<GSPLIT;p++) s += Gpart[(size_t)p*DIM*DIM + i];
  const float invN = 1.0f/32768.0f;
  float mr = meansum[r]*invN, mc = meansum[c]*invN;
  G[i] = s*invN - mr*mc;
}

// v_out = G * v_in   (one wave per row)
__global__ void k_mv(const float* __restrict__ G, const float* __restrict__ vin,
                     float* __restrict__ vout){
  __shared__ float vs[DIM];
  int t = threadIdx.x;
  for (int i=t;i<DIM;i+=256) vs[i] = vin[i];
  __syncthreads();
  int row = blockIdx.x*4 + (t>>6), l = t&63;
  const float* g = G + (size_t)row*DIM;
  float s = 0.f;
  for (int j=0;j<12;j++) s += g[l + j*64]*vs[l + j*64];
  s = waveSum(s);
  if (l==0) vout[row] = s;
}

// scal[0] = mu . v
__global__ void k_muv(const float* __restrict__ meansum, const float* __restrict__ v,
                      float* __restrict__ scal){
  __shared__ float red[256];
  int t = threadIdx.x;
  float s = 0.f;
  for (int i=t;i<DIM;i+=256) s += meansum[i]*(1.0f/32768.0f)*v[i];
  float r = blockSum(s, red);
  if (t==0) scal[0] = r;
}

// u[n] = X[n,:].v - mu.v ; fused global min/max
__global__ void k_u(const unsigned short* __restrict__ hiT, const unsigned short* __restrict__ loT,
                    const float* __restrict__ v, const float* __restrict__ scal,
                    float* __restrict__ u, unsigned int* __restrict__ minmax){
  __shared__ float vs[DIM];
  int t = threadIdx.x;
  for (int i=t;i<DIM;i+=256) vs[i] = v[i];
  __syncthreads();
  size_t n = (size_t)blockIdx.x*256 + t;
  float acc = 0.f;
  for (int c=0;c<DIM;c++){
    size_t o = (size_t)c*BN_TOT + n;
    acc += (bf2f(hiT[o]) + bf2f(loT[o])) * vs[c];
  }
  float val = acc - scal[0];
  u[n] = val;
  float mn = val, mx = val;
  for (int m=32;m;m>>=1){
    mn = fminf(mn, __shfl_xor(mn, m, 64));
    mx = fmaxf(mx, __shfl_xor(mx, m, 64));
  }
  __shared__ float smn[4], smx[4];
  int w = t>>6;
  if ((t&63)==0){ smn[w]=mn; smx[w]=mx; }
  __syncthreads();
  if (t==0){
    for (int k=1;k<4;k++){ mn = fminf(mn, smn[k]); mx = fmaxf(mx, smx[k]); }
    atomicMin(&minmax[0], fenc(mn));
    atomicMax(&minmax[1], fenc(mx));
  }
}

// patch labels + per-class counts (fg only)
__global__ void k_pl(const float* __restrict__ u, const int* __restrict__ labels,
                     const unsigned int* __restrict__ minmax, int* __restrict__ pl,
                     int* __restrict__ cnt){
  int n = blockIdx.x*256 + threadIdx.x;
  float umin = fdec(minmax[0]), umax = fdec(minmax[1]);
  float us = (u[n]-umin)/(umax-umin);
  int c = (us < 0.5f) ? labels[n>>10] : (NCLS-1);
  pl[n] = c;
  if (c < NCLS-1) atomicAdd(&cnt[c], 1);
}

// prefix offsets + present bitmap
__global__ void k_offs(const int* __restrict__ cnt, int* __restrict__ offs,
                       const int* __restrict__ labels, int* __restrict__ present){
  if (threadIdx.x == 0){
    int acc = 0;
    for (int c=0;c<NCLS-1;c++){ offs[c] = acc; acc += cnt[c]; }
    offs[NCLS-1] = acc;
  }
  if (threadIdx.x < 32) atomicOr(&present[labels[threadIdx.x]], 1);
}

__global__ void k_scatter(const int* __restrict__ pl, const int* __restrict__ offs,
                          int* __restrict__ cur, int* __restrict__ idx){
  int n = blockIdx.x*256 + threadIdx.x;
  int c = pl[n];
  if (c < NCLS-1){
    int p = offs[c] + atomicAdd(&cur[c], 1);
    idx[p] = n;
  }
}

// own-class logits -> q0 = exp(L/eps), stored in class-sorted order
__global__ void k_qlog(const int* __restrict__ idx, const int* __restrict__ offs,
                       const int* __restrict__ pl, const unsigned short* __restrict__ ptn,
                       const unsigned short* __restrict__ protn, float* __restrict__ q){
  int i = blockIdx.x*4 + (threadIdx.x>>6);
  int l = threadIdx.x & 63;
  int total = offs[NCLS-1];
  if (i >= total) return;
  int n = idx[i];
  int c = pl[n];
  const unsigned short* pr = ptn + (size_t)n*DIM;
  float x[12];
  for (int j=0;j<12;j++) x[j] = bf2f(pr[l + j*64]);
  for (int k=0;k<KP;k++){
    const unsigned short* wv = protn + (size_t)(c*KP + k)*DIM;
    float s = 0.f;
    for (int j=0;j<12;j++) s += x[j]*bf2f(wv[l + j*64]);
    s = waveSum(s);
    if (l==0) q[(size_t)i*KP + k] = expf(s*20.0f);
  }
}

// per-class sinkhorn in place on its sorted segment
__global__ void k_sink(const int* __restrict__ cnt, const int* __restrict__ offs,
                       float* __restrict__ q){
  __shared__ float red[256];
  __shared__ float colf[KP];
  int c = blockIdx.x;
  int nc = cnt[c];
  if (nc == 0) return;
  int n0 = offs[c];
  float* Q = q + (size_t)n0*KP;
  int t = threadIdx.x;
  int tot5 = nc*KP;
  float s = 0.f;
  for (int i=t;i<tot5;i+=256) s += Q[i];
  float total = blockSum(s, red);
  float sc = 1.0f/fmaxf(total, 1e-9f);
  for (int i=t;i<tot5;i+=256) Q[i] *= sc;
  __syncthreads();
  float ncf = (float)nc;
  for (int it=0; it<3; it++){
    float cs[KP] = {0,0,0,0,0};
    for (int i=t;i<nc;i+=256){
      const float* row = Q + (size_t)i*KP;
      #pragma unroll
      for (int k=0;k<KP;k++) cs[k] += row[k];
    }
    for (int k=0;k<KP;k++){
      float v = blockSum(cs[k], red);
      if (t==0) colf[k] = 1.0f/(fmaxf(v,1e-9f)*(float)KP);
    }
    __syncthreads();
    for (int i=t;i<nc;i+=256){
      float* row = Q + (size_t)i*KP;
      float qq[KP]; float rs = 0.f;
      #pragma unroll
      for (int k=0;k<KP;k++){ qq[k] = row[k]*colf[k]; rs += qq[k]; }
      float rf = 1.0f/(fmaxf(rs,1e-9f)*ncf);
      #pragma unroll
      for (int k=0;k<KP;k++) row[k] = qq[k]*rf;
    }
    __syncthreads();
  }
  for (int i=t;i<tot5;i+=256) Q[i] *= ncf;
}

// P4[s][c][k][d] = partial sum over this split's class-c rows of Q[n,k]*ptn[n,d]
__global__ void k_pnew(const int* __restrict__ cnt, const int* __restrict__ offs,
                       const int* __restrict__ present, const int* __restrict__ idx,
                       const float* __restrict__ q, const unsigned short* __restrict__ ptn,
                       float* __restrict__ P4){
  int c = blockIdx.y, s = blockIdx.x;
  if (!present[c]) return;
  int nc = cnt[c], n0 = offs[c];
  int r0 = n0 + (nc*s)/PSPLIT;
  int r1 = n0 + (nc*(s+1))/PSPLIT;
  int t = threadIdx.x;
  float acc[KP][3];
  #pragma unroll
  for (int k=0;k<KP;k++){ acc[k][0]=0.f; acc[k][1]=0.f; acc[k][2]=0.f; }
  for (int i=r0; i<r1; ++i){
    int n = idx[i];
    float qv[KP];
    #pragma unroll
    for (int k=0;k<KP;k++) qv[k] = q[(size_t)i*KP + k];
    const unsigned short* row = ptn + (size_t)n*DIM;
    #pragma unroll
    for (int j=0;j<3;j++){
      float x = bf2f(row[t + j*256]);
      #pragma unroll
      for (int k=0;k<KP;k++) acc[k][j] += qv[k]*x;
    }
  }
  float* out = P4 + ((size_t)(s*NCLS + c)*KP)*DIM;
  #pragma unroll
  for (int k=0;k<KP;k++)
    #pragma unroll
    for (int j=0;j<3;j++)
      out[(size_t)k*DIM + t + j*256] = acc[k][j];
}

// new_prototypes = present ? 0.9*p + 0.1*sum_s(P4[s]) : p
__global__ void k_ema(const float* __restrict__ protos, const float* __restrict__ P4,
                      const int* __restrict__ present, float* __restrict__ out){
  int i = blockIdx.x*256 + threadIdx.x;
  if (i >= NCLS*KP*DIM) return;
  int c = i / (KP*DIM);
  float p = protos[i];
  if (present[c]){
    float s = 0.f;
    #pragma unroll
    for (int sp=0; sp<PSPLIT; sp++) s += P4[(size_t)sp*NCLS*KP*DIM + i];
    out[i] = 0.9f*p + 0.1f*s;
  } else {
    out[i] = p;
  }
}

// decode ipl + class_logits
__global__ void k_final(const unsigned int* __restrict__ ipl_enc, float* __restrict__ out){
  int i = blockIdx.x*256 + threadIdx.x;
  if (i < 32*NCLS*KP){
    int b = i / (NCLS*KP), ck = i % (NCLS*KP);
    out[32*NCLS + i] = fdec(ipl_enc[b*CKPAD + ck]);
  }
  if (i < 32*NCLS){
    int b = i / NCLS, c = i % NCLS;
    float s = 0.f;
    #pragma unroll
    for (int k=0;k<KP;k++) s += fdec(ipl_enc[b*CKPAD + c*KP + k]);
    out[b*NCLS + c] = s;
  }
}

// ---------- launch ----------
extern "C" void kernel_launch(void* const* d_in, const int* in_sizes, int n_in,
                              void* d_out, int out_size, void* d_ws, size_t ws_size,
                              hipStream_t stream){
  (void)in_sizes; (void)n_in; (void)out_size; (void)ws_size;
  const float* X = (const float*)d_in[0];
  const float* protos = (const float*)d_in[1];
  const int* labels_raw = (const int*)d_in[2];
  float* out = (float*)d_out;

  char* w = (char*)d_ws;
  size_t off = 0;
  auto alloc = [&](size_t bytes)->void*{
    void* p = (void*)(w + off);
    off = (off + bytes + 255) & ~(size_t)255;
    return p;
  };
  unsigned short* hiT   = (unsigned short*)alloc((size_t)DIM*BN_TOT*2);
  unsigned short* loT   = (unsigned short*)alloc((size_t)DIM*BN_TOT*2);
  unsigned short* ptn   = (unsigned short*)alloc((size_t)BN_TOT*DIM*2);
  unsigned short* protn = (unsigned short*)alloc((size_t)CKPAD*DIM*2);
  float* Gpart   = (float*)alloc((size_t)GSPLIT*DIM*DIM*4);
  float* G       = (float*)alloc((size_t)DIM*DIM*4);
  float* meansum = (float*)alloc(DIM*4);
  float* vA      = (float*)alloc(DIM*4);
  float* vB      = (float*)alloc(DIM*4);
  float* scal    = (float*)alloc(256);
  int* cnt       = (int*)alloc(1024);
  int* cur       = (int*)alloc(1024);
  int* offs      = (int*)alloc(1024);
  int* present   = (int*)alloc(1024);
  int* labc      = (int*)alloc(256);
  unsigned int* minmax  = (unsigned int*)alloc(256);
  unsigned int* ipl_enc = (unsigned int*)alloc((size_t)32*CKPAD*4);

  // buffers only live AFTER k_gfix has consumed Gpart: alias into Gpart space
  {
    char* gb = (char*)Gpart;
    size_t goff = 0;
    auto galloc = [&](size_t bytes)->void*{
      void* p = (void*)(gb + goff);
      goff = (goff + bytes + 255) & ~(size_t)255;
      return p;
    };
    float* u_  = (float*)galloc(BN_TOT*4);
    int* pl_   = (int*)galloc(BN_TOT*4);
    int* idx_  = (int*)galloc(BN_TOT*4);
    float* q_  = (float*)galloc((size_t)BN_TOT*KP*4);
    float* P4_ = (float*)galloc((size_t)PSPLIT*NCLS*KP*DIM*4);

    dim3 b256(256);
    k_setup<<<dim3(128), b256, 0, stream>>>(ipl_enc, cnt, cur, present, minmax, meansum,
                                            labels_raw, labc, vA);
    k_proto<<<dim3(CKPAD), dim3(64), 0, stream>>>(protos, protn);
    k_trans<<<dim3(512,12), b256, 0, stream>>>(X, hiT, loT, meansum);
    k_ptn<<<dim3(8192), b256, 0, stream>>>(X, ptn);
    k_gemm_logits<<<dim3(8,256), b256, 0, stream>>>(ptn, protn, ipl_enc);
    k_gemm_G<<<dim3(21*GSPLIT), b256, 0, stream>>>(hiT, loT, Gpart);
    k_gfix<<<dim3(2304), b256, 0, stream>>>(Gpart, meansum, G);
    for (int it=0; it<10; it++){
      float* src = (it&1) ? vB : vA;
      float* dst = (it&1) ? vA : vB;
      k_mv<<<dim3(192), b256, 0, stream>>>(G, src, dst);
    }
    k_muv<<<dim3(1), b256, 0, stream>>>(meansum, vA, scal);
    k_u<<<dim3(128), b256, 0, stream>>>(hiT, loT, vA, scal, u_, minmax);
    k_pl<<<dim3(128), b256, 0, stream>>>(u_, labc, minmax, pl_, cnt);
    k_offs<<<dim3(1), b256, 0, stream>>>(cnt, offs, labc, present);
    k_scatter<<<dim3(128), b256, 0, stream>>>(pl_, offs, cur, idx_);
    k_qlog<<<dim3(8192), b256, 0, stream>>>(idx_, offs, pl_, ptn, protn, q_);
    k_sink<<<dim3(200), b256, 0, stream>>>(cnt, offs, q_);
    k_pnew<<<dim3(PSPLIT,NCLS), b256, 0, stream>>>(cnt, offs, present, idx_, q_, ptn, P4_);
    k_ema<<<dim3(3015), b256, 0, stream>>>(protos, P4_, present, out + 32*NCLS + 32*NCLS*KP);
    k_final<<<dim3(126), b256, 0, stream>>>(ipl_enc, out);
  }
}